// Round 1
// 677.195 us; speedup vs baseline: 1.0101x; 1.0101x over previous
//
#include <hip/hip_runtime.h>
#include <math.h>

// Problem: B=32, A=2048, D2=2048 (two heads of D=1024), TOP_K=5, fp32.
// a_embeds_target = 512 MB read per call >> all else -> HBM-bound.
// Roofline: 512 MB / 6.3 TB/s ~= 81 us for kernel 1; kernel 2 reads 768 KB.
// NOTE (R1 post-mortem): bench dur_us includes ~500 us of harness reset
// (2 GB d_ws 0xAA fill ~335 us + 512 MB d_in restore ~160 us per iteration);
// our controllable share is kernel time only (~185 us residual at R1).
// R2 theory: residual >> 90 us roofline -> kernel 1 at ~50% of achievable BW.
// Cause hypothesis: monolithic 64-load unroll -> VGPR-pressure occupancy loss
// + clumped waitcnt drains limit per-wave MLP. Fix: explicit 2-deep
// double-buffered pipeline (~120 VGPR budget) + nontemporal stream loads.
#define BATCH 32
#define NACT  2048
#define DIM2  2048   // 2*D
#define TOPK  5
#define ACTIONS_PER_BLOCK 32   // 4 waves x 8 actions
#define APW   8                // actions per wave

// ext_vector_type instead of HIP's struct float4 so that
// __builtin_nontemporal_load accepts it (clang requires scalar/vector type).
typedef float floatx4 __attribute__((ext_vector_type(4)));

// ---------------------------------------------------------------------------
// Kernel 1: logits[h][b][a] = dot(s[b, hD:(h+1)D], a_emb[b, a, hD:(h+1)D]).
// One wave per 8 actions. Lane l owns columns l*4 + 256*i (i=0..7) as float4.
// Explicit software pipeline: while FMA-ing action j's 8 float4 (bufA/bufB),
// the 8 loads for action j+1 are already in flight -> steady 8-16 outstanding
// loads/wave, bounded VGPR (~120). a_emb loads are nontemporal (read-once
// stream, no L1/L2/LLC allocation). All 16 butterfly reductions deferred to
// the end as independent chains (ILP hides ds_swizzle latency).
// ---------------------------------------------------------------------------
__global__ __launch_bounds__(256) void logits_kernel(
    const float* __restrict__ s_embed,   // [B, DIM2]
    const float* __restrict__ a_emb,     // [B, A, DIM2]
    float* __restrict__ logits)          // [2, B, A] in workspace
{
    const int tile  = blockIdx.x;                 // 32*64 tiles
    const int b     = tile >> 6;                  // NACT/ACTIONS_PER_BLOCK=64
    const int a0    = (tile & 63) * ACTIONS_PER_BLOCK;
    const int wave  = threadIdx.x >> 6;
    const int lane  = threadIdx.x & 63;

    // s_embed[b] fragment for this lane: 8 x float4 = 32 floats in VGPRs.
    // Normal (cached) loads: row is reused by 64 blocks -> L2 hits.
    floatx4 sreg[8];
    const float* srow = s_embed + (size_t)b * DIM2 + lane * 4;
    #pragma unroll
    for (int i = 0; i < 8; ++i)
        sreg[i] = *(const floatx4*)(srow + 256 * i);

    const int abase = a0 + wave * APW;
    const float* pbase = a_emb + ((size_t)b * NACT + abase) * DIM2 + lane * 4;

    float acc1[APW], acc2[APW];

    // Two named buffers; after full unroll every index/pointer is
    // compile-time constant (no scratch spill from dynamic indexing).
    floatx4 bufA[8], bufB[8];

    // Prologue: issue action 0's 8 loads.
    #pragma unroll
    for (int i = 0; i < 8; ++i)
        bufA[i] = __builtin_nontemporal_load((const floatx4*)(pbase + 256 * i));

    #pragma unroll
    for (int j = 0; j < APW; ++j) {
        const floatx4* cur = (j & 1) ? bufB : bufA;   // folds after unroll
        floatx4*       nxt = (j & 1) ? bufA : bufB;

        // Issue next action's loads BEFORE consuming current buffer:
        // compiler emits s_waitcnt vmcnt(8), keeping 8 loads in flight.
        if (j + 1 < APW) {
            const float* pn = pbase + (size_t)(j + 1) * DIM2;
            #pragma unroll
            for (int i = 0; i < 8; ++i)
                nxt[i] = __builtin_nontemporal_load((const floatx4*)(pn + 256 * i));
        }

        float d1 = 0.f, d2 = 0.f;
        #pragma unroll
        for (int i = 0; i < 4; ++i) {                 // head 1: cols [0,1024)
            floatx4 v = cur[i];
            d1 += v.x * sreg[i].x + v.y * sreg[i].y + v.z * sreg[i].z + v.w * sreg[i].w;
        }
        #pragma unroll
        for (int i = 4; i < 8; ++i) {                 // head 2: cols [1024,2048)
            floatx4 v = cur[i];
            d2 += v.x * sreg[i].x + v.y * sreg[i].y + v.z * sreg[i].z + v.w * sreg[i].w;
        }
        acc1[j] = d1;
        acc2[j] = d2;
    }

    // Batched butterfly reductions: 16 independent chains.
    #pragma unroll
    for (int off = 32; off >= 1; off >>= 1) {
        #pragma unroll
        for (int j = 0; j < APW; ++j) {
            acc1[j] += __shfl_xor(acc1[j], off, 64);
            acc2[j] += __shfl_xor(acc2[j], off, 64);
        }
    }

    if (lane == 0) {
        float* o1 = logits + (size_t)b * NACT + abase;
        float* o2 = o1 + (size_t)BATCH * NACT;
        #pragma unroll
        for (int j = 0; j < APW; ++j) { o1[j] = acc1[j]; o2[j] = acc2[j]; }
    }
}

// ---------------------------------------------------------------------------
// Kernel 2: one wave per (head,row). Row (2048 floats) lives in registers
// (32/lane, strided: lane l holds elements 64k+l). 5x shfl-argmax with
// lowest-index tie-break (matches jax.lax.top_k), then masked LSE with
// UNMASKED-max stabilizer and eps clamp:
//   out = maxlogit + alpha * log(max(sum_{top5 & avail} exp((x-maxlogit)/alpha), 1e-10))
// No LDS, no __syncthreads.
// ---------------------------------------------------------------------------
__global__ __launch_bounds__(256) void topk_lse_kernel(
    const float* __restrict__ logits,   // [2, B, A]
    const int* __restrict__ avail,      // [B, A] (bool as int32)
    const float* __restrict__ alpha_p,  // [1]
    float* __restrict__ out)            // [2*B]: v1 then v2
{
    const int row  = blockIdx.x * 4 + (threadIdx.x >> 6);  // 0..63 = h*32+b
    const int lane = threadIdx.x & 63;
    const int b    = row & 31;

    const float* x = logits + (size_t)row * NACT;
    float v[32];
    #pragma unroll
    for (int k = 0; k < 32; ++k) v[k] = x[k * 64 + lane];  // coalesced

    const float alpha = alpha_p[0];
    float smax = 0.f, ssum = 0.f;

    for (int it = 0; it < TOPK; ++it) {
        // lane-local argmax; k ascending + strict '>' keeps lowest index
        float best = -INFINITY; int bi = 1 << 30;
        #pragma unroll
        for (int k = 0; k < 32; ++k) {
            float val = v[k];
            if (val > best) { best = val; bi = k * 64 + lane; }
        }
        // wave argmax, tie -> lowest linear index
        #pragma unroll
        for (int off = 32; off >= 1; off >>= 1) {
            float v2 = __shfl_xor(best, off, 64);
            int   i2 = __shfl_xor(bi,   off, 64);
            if (v2 > best || (v2 == best && i2 < bi)) { best = v2; bi = i2; }
        }
        if (it == 0) smax = best;                 // unmasked global max
        if (avail[(size_t)b * NACT + bi])         // broadcast load
            ssum += expf((best - smax) / alpha);
        #pragma unroll
        for (int k = 0; k < 32; ++k)              // extract without dyn-index
            if (k * 64 + lane == bi) v[k] = -INFINITY;
    }

    if (lane == 0)
        out[row] = smax + alpha * logf(fmaxf(ssum, 1e-10f));
}

// ---------------------------------------------------------------------------
extern "C" void kernel_launch(void* const* d_in, const int* in_sizes, int n_in,
                              void* d_out, int out_size, void* d_ws, size_t ws_size,
                              hipStream_t stream) {
    const float* s_embed = (const float*)d_in[0];   // [32, 2048] fp32
    const float* a_emb   = (const float*)d_in[1];   // [32, 2048, 2048] fp32
    const int*   avail   = (const int*)d_in[2];     // [32, 2048] bool->int32
    const float* alpha   = (const float*)d_in[3];   // [1] fp32
    float*       out     = (float*)d_out;           // [64] fp32 (v1 ++ v2)
    float*       logits  = (float*)d_ws;            // [2, 32, 2048] = 512 KB

    logits_kernel<<<BATCH * (NACT / ACTIONS_PER_BLOCK), 256, 0, stream>>>(
        s_embed, a_emb, logits);
    topk_lse_kernel<<<16, 256, 0, stream>>>(logits, avail, alpha, out);
}